// Round 1
// baseline (240.860 us; speedup 1.0000x reference)
//
#include <hip/hip_runtime.h>
#include <math.h>

#define Bb 4
#define Cc 192
#define NN 1024
#define HD 384
#define NH 4
#define FF 1536   // NH*HD
#define KN 16
#define BN_EPS 1e-5f

// ---------------------------------------------------------------- fc1 + BN
// y[b,n,c] = BN1( sum_k xf[b,n,k]*W1[c,k] + b1[c] ), xf[b,n,k] = x[b,k,n]
__global__ __launch_bounds__(192) void k_fc1(
    const float* __restrict__ x, const float* __restrict__ W1,
    const float* __restrict__ b1, const float* __restrict__ bn1,
    float* __restrict__ y) {
  int bb = blockIdx.x;                 // 256 blocks: 16 rows each
  int b  = bb / (NN / 16);
  int n0 = (bb % (NN / 16)) * 16;
  int c  = threadIdx.x;                // 0..191
  __shared__ float xs[16][Cc];
  const float* xp = x + ((size_t)b * Cc + c) * NN + n0;
#pragma unroll
  for (int r = 0; r < 16; ++r) xs[r][c] = xp[r];
  __syncthreads();
  float acc[16];
#pragma unroll
  for (int r = 0; r < 16; ++r) acc[r] = 0.f;
  const float* w = W1 + (size_t)c * Cc;
  for (int k = 0; k < Cc; ++k) {
    float wv = w[k];
#pragma unroll
    for (int r = 0; r < 16; ++r) acc[r] = fmaf(xs[r][k], wv, acc[r]);
  }
  float s  = bn1[c] / sqrtf(bn1[3 * Cc + c] + BN_EPS);
  float mm = bn1[2 * Cc + c];
  float be = bn1[Cc + c];
  float bias = b1[c];
#pragma unroll
  for (int r = 0; r < 16; ++r) {
    y[((size_t)b * NN + n0 + r) * Cc + c] = (acc[r] + bias - mm) * s + be;
  }
}

// ---------------------------------------------------------------- row sums of y^2
__global__ __launch_bounds__(64) void k_sq(const float* __restrict__ y,
                                           float* __restrict__ sq) {
  int bn = blockIdx.x;
  int lane = threadIdx.x;
  const float* yp = y + (size_t)bn * Cc;
  float s = 0.f;
  for (int k = lane; k < Cc; k += 64) { float v = yp[k]; s = fmaf(v, v, s); }
#pragma unroll
  for (int off = 32; off; off >>= 1) s += __shfl_down(s, off);
  if (lane == 0) sq[bn] = s;
}

// ---------------------------------------------------------------- h = y @ Wg
__global__ __launch_bounds__(256) void k_hgemm(const float* __restrict__ y,
                                               const float* __restrict__ Wg,
                                               float* __restrict__ h) {
  int rt = blockIdx.x, ct = blockIdx.y;   // 64 row-tiles x 24 col-tiles
  int r0 = rt * 64, c0 = ct * 64;
  __shared__ float ys[64 * Cc];           // 48 KB
  for (int i = threadIdx.x; i < 64 * Cc; i += 256)
    ys[i] = y[(size_t)r0 * Cc + i];
  __syncthreads();
  int tx = threadIdx.x % 64, ty = threadIdx.x / 64;
  float acc[16];
#pragma unroll
  for (int i = 0; i < 16; ++i) acc[i] = 0.f;
  for (int k = 0; k < Cc; ++k) {
    float wv = Wg[(size_t)k * FF + c0 + tx];
#pragma unroll
    for (int i = 0; i < 16; ++i)
      acc[i] = fmaf(ys[(ty + 4 * i) * Cc + k], wv, acc[i]);
  }
#pragma unroll
  for (int i = 0; i < 16; ++i) {
    int r = r0 + ty + 4 * i;
    h[(size_t)r * FF + c0 + tx] = acc[i];
  }
}

// ---------------------------------------------------------------- a_src / a_dst
__global__ __launch_bounds__(256) void k_attn_coef(
    const float* __restrict__ h, const float* __restrict__ att_src,
    const float* __restrict__ att_dst, float* __restrict__ asrc,
    float* __restrict__ adst) {
  int bn = blockIdx.x;
  int head = threadIdx.x / 64, lane = threadIdx.x % 64;
  const float* hp = h + (size_t)bn * FF + head * HD;
  const float* as = att_src + head * HD;
  const float* ad = att_dst + head * HD;
  float s1 = 0.f, s2 = 0.f;
  for (int d = lane; d < HD; d += 64) {
    float v = hp[d];
    s1 = fmaf(v, as[d], s1);
    s2 = fmaf(v, ad[d], s2);
  }
#pragma unroll
  for (int off = 32; off; off >>= 1) {
    s1 += __shfl_down(s1, off);
    s2 += __shfl_down(s2, off);
  }
  if (lane == 0) {
    asrc[bn * NH + head] = s1;
    adst[bn * NH + head] = s2;
  }
}

// ---------------------------------------------------------------- pairwise distances
// dist[b,n,m] = sq[n] + sq[m] - 2 * dot(y_n, y_m); K chunked in 64s.
__global__ __launch_bounds__(256) void k_dist(const float* __restrict__ y,
                                              const float* __restrict__ sq,
                                              float* __restrict__ dist) {
  int b = blockIdx.z, nt = blockIdx.y, mt = blockIdx.x;
  int n0 = nt * 64, m0 = mt * 64;
  __shared__ float yn[64][65];
  __shared__ float ym[64][65];
  const float* ybase = y + (size_t)b * NN * Cc;
  int tx = threadIdx.x % 64, ty = threadIdx.x / 64;
  float acc[16];
#pragma unroll
  for (int i = 0; i < 16; ++i) acc[i] = 0.f;
  for (int kc = 0; kc < Cc; kc += 64) {
    __syncthreads();
    for (int i = threadIdx.x; i < 64 * 64; i += 256) {
      int r = i >> 6, k = i & 63;
      yn[r][k] = ybase[(size_t)(n0 + r) * Cc + kc + k];
      ym[r][k] = ybase[(size_t)(m0 + r) * Cc + kc + k];
    }
    __syncthreads();
    for (int k = 0; k < 64; ++k) {
      float mv = ym[tx][k];
#pragma unroll
      for (int i = 0; i < 16; ++i)
        acc[i] = fmaf(yn[ty + 4 * i][k], mv, acc[i]);
    }
  }
  float sm = sq[b * NN + m0 + tx];
#pragma unroll
  for (int i = 0; i < 16; ++i) {
    int n = n0 + ty + 4 * i;
    float d = sq[b * NN + n] + sm - 2.f * acc[i];
    dist[((size_t)b * NN + n) * NN + m0 + tx] = d;
  }
}

// ---------------------------------------------------------------- top-16 smallest per row
__global__ __launch_bounds__(64) void k_topk(const float* __restrict__ dist,
                                             int* __restrict__ idx) {
  int bn = blockIdx.x;
  int lane = threadIdx.x;
  const float* dp = dist + (size_t)bn * NN;
  float dv[16];
#pragma unroll
  for (int j = 0; j < 16; ++j) dv[j] = dp[lane + 64 * j];
  for (int sel = 0; sel < KN; ++sel) {
    float bv = INFINITY;
    int bi = 0x7fffffff;
#pragma unroll
    for (int j = 0; j < 16; ++j) {
      int m = lane + 64 * j;
      if (dv[j] < bv || (dv[j] == bv && m < bi)) { bv = dv[j]; bi = m; }
    }
#pragma unroll
    for (int off = 32; off; off >>= 1) {
      float ov = __shfl_xor(bv, off);
      int oi   = __shfl_xor(bi, off);
      if (ov < bv || (ov == bv && oi < bi)) { bv = ov; bi = oi; }
    }
    if (lane == 0) idx[bn * KN + sel] = bi;
#pragma unroll
    for (int j = 0; j < 16; ++j)
      if (lane + 64 * j == bi) dv[j] = INFINITY;   // static index, no scratch
  }
}

// ---------------------------------------------------------------- GAT aggregate + BN + GELU
__global__ __launch_bounds__(128) void k_gat(
    const float* __restrict__ h, const float* __restrict__ asrc,
    const float* __restrict__ adst, const int* __restrict__ idx,
    const float* __restrict__ bg, const float* __restrict__ bng,
    float* __restrict__ g) {
  int bn = blockIdx.x;
  int b = bn / NN;
  __shared__ int nb[KN];
  __shared__ float attn[KN][NH];
  int t = threadIdx.x;
  if (t < KN) nb[t] = idx[bn * KN + t];
  __syncthreads();
  if (t < KN * NH) {
    int k = t % KN, hd = t / KN;
    float e = asrc[((size_t)b * NN + nb[k]) * NH + hd] +
              adst[(size_t)bn * NH + hd];
    e = (e >= 0.f) ? e : 0.2f * e;      // leaky_relu 0.2
    attn[k][hd] = e;
  }
  __syncthreads();
  if (t < NH) {
    float mx = -INFINITY;
    for (int k = 0; k < KN; ++k) mx = fmaxf(mx, attn[k][t]);
    float s = 0.f;
    for (int k = 0; k < KN; ++k) {
      float ev = expf(attn[k][t] - mx);
      attn[k][t] = ev;
      s += ev;
    }
    float inv = 1.f / s;
    for (int k = 0; k < KN; ++k) attn[k][t] *= inv;
  }
  __syncthreads();
  for (int d = t; d < HD; d += 128) {
    float acc = 0.f;
    for (int k = 0; k < KN; ++k) {
      size_t base = ((size_t)b * NN + nb[k]) * FF;
#pragma unroll
      for (int hh = 0; hh < NH; ++hh)
        acc = fmaf(attn[k][hh], h[base + hh * HD + d], acc);
    }
    float val = acc * 0.25f + bg[d];                       // mean over heads + bias
    float sc = bng[d] / sqrtf(bng[3 * HD + d] + BN_EPS);
    val = (val - bng[2 * HD + d]) * sc + bng[HD + d];      // BN
    val = 0.5f * val * (1.f + erff(val * 0.7071067811865475f)); // exact GELU
    g[(size_t)bn * HD + d] = val;
  }
}

// ---------------------------------------------------------------- fc2 + BN + residual + transpose
__global__ __launch_bounds__(192) void k_fc2(
    const float* __restrict__ g, const float* __restrict__ W2,
    const float* __restrict__ b2, const float* __restrict__ bn2,
    const float* __restrict__ x, float* __restrict__ out) {
  int bb = blockIdx.x;
  int b  = bb / (NN / 16);
  int n0 = (bb % (NN / 16)) * 16;
  int c  = threadIdx.x;
  __shared__ float gs[16 * HD];   // 24 KB
  for (int i = threadIdx.x; i < 16 * HD; i += 192)
    gs[i] = g[((size_t)b * NN + n0) * HD + i];
  __syncthreads();
  float acc[16];
#pragma unroll
  for (int r = 0; r < 16; ++r) acc[r] = 0.f;
  const float* w = W2 + (size_t)c * HD;
  for (int k = 0; k < HD; ++k) {
    float wv = w[k];
#pragma unroll
    for (int r = 0; r < 16; ++r) acc[r] = fmaf(gs[r * HD + k], wv, acc[r]);
  }
  float s  = bn2[c] / sqrtf(bn2[3 * Cc + c] + BN_EPS);
  float mm = bn2[2 * Cc + c];
  float be = bn2[Cc + c];
  float bias = b2[c];
  const float* xp = x + ((size_t)b * Cc + c) * NN + n0;
  float* op = out + ((size_t)b * Cc + c) * NN + n0;
#pragma unroll
  for (int r = 0; r < 16; ++r) {
    op[r] = (acc[r] + bias - mm) * s + be + xp[r];
  }
}

extern "C" void kernel_launch(void* const* d_in, const int* in_sizes, int n_in,
                              void* d_out, int out_size, void* d_ws, size_t ws_size,
                              hipStream_t stream) {
  const float* x       = (const float*)d_in[0];
  const float* W1      = (const float*)d_in[1];
  const float* b1      = (const float*)d_in[2];
  const float* bn1     = (const float*)d_in[3];
  const float* Wg      = (const float*)d_in[4];
  const float* att_src = (const float*)d_in[5];
  const float* att_dst = (const float*)d_in[6];
  const float* bg      = (const float*)d_in[7];
  const float* bng     = (const float*)d_in[8];
  const float* W2      = (const float*)d_in[9];
  const float* b2      = (const float*)d_in[10];
  const float* bn2     = (const float*)d_in[11];
  float* out = (float*)d_out;

  // workspace layout (floats); g reuses the dist region (dist dead after topk)
  float* ws   = (float*)d_ws;
  float* y    = ws;                        // 786432
  float* h    = y + 786432;                // 6291456
  float* sq   = h + 6291456;               // 4096
  float* asrc = sq + 4096;                 // 16384
  float* adst = asrc + 16384;              // 16384
  float* dist = adst + 16384;              // 4194304
  float* g    = dist;                      // 1572864 (reuse)
  int*   idx  = (int*)(dist + 4194304);    // 65536 ints

  k_fc1<<<256, 192, 0, stream>>>(x, W1, b1, bn1, y);
  k_sq<<<Bb * NN, 64, 0, stream>>>(y, sq);
  k_hgemm<<<dim3(64, 24), 256, 0, stream>>>(y, Wg, h);
  k_attn_coef<<<Bb * NN, 256, 0, stream>>>(h, att_src, att_dst, asrc, adst);
  k_dist<<<dim3(16, 16, 4), 256, 0, stream>>>(y, sq, dist);
  k_topk<<<Bb * NN, 64, 0, stream>>>(dist, idx);
  k_gat<<<Bb * NN, 128, 0, stream>>>(h, asrc, adst, idx, bg, bng, g);
  k_fc2<<<256, 192, 0, stream>>>(g, W2, b2, bn2, x, out);
}

// Round 2
// 191.279 us; speedup vs baseline: 1.2592x; 1.2592x over previous
//
#include <hip/hip_runtime.h>
#include <math.h>

#define Bb 4
#define Cc 192
#define NN 1024
#define HD 384
#define NH 4
#define FF 1536   // NH*HD
#define KN 16
#define BN_EPS 1e-5f

// ---------------------------------------------------------------- fc1 + BN
// y[b,n,c] = BN1( sum_k x[b,k,n]*W1[c,k] + b1[c] )
// A[k][n] = x[b][k][n] (direct, k-major already), B[k][c] = W1[c][k] (transpose-staged)
__global__ __launch_bounds__(256) void k_fc1(
    const float* __restrict__ x, const float* __restrict__ W1,
    const float* __restrict__ b1, const float* __restrict__ bn1,
    float* __restrict__ y) {
  int nt = blockIdx.x, ct = blockIdx.y, b = blockIdx.z;
  int n0 = nt * 64, c0 = ct * 64;
  __shared__ float As[64][64];   // [k][n]
  __shared__ float Bs[64][64];   // [k][c]
  int t = threadIdx.x;
  int tx = t & 15, ty = t >> 4;
  float acc[4][4] = {};
  for (int k0 = 0; k0 < Cc; k0 += 64) {
    __syncthreads();
#pragma unroll
    for (int i = 0; i < 4; ++i) {
      int fi = t * 4 + i;
      int r = fi >> 4, q = fi & 15;
      // A: x[(b*Cc + k0+r)*NN + n0 + q*4] direct k-major
      float4 av = *(const float4*)&x[((size_t)b * Cc + k0 + r) * NN + n0 + q * 4];
      *(float4*)&As[r][q * 4] = av;
      // B: W1[(c0+r)][k0 + q*4] -> transpose
      float4 bv = *(const float4*)&W1[(size_t)(c0 + r) * Cc + k0 + q * 4];
      Bs[q * 4 + 0][r] = bv.x; Bs[q * 4 + 1][r] = bv.y;
      Bs[q * 4 + 2][r] = bv.z; Bs[q * 4 + 3][r] = bv.w;
    }
    __syncthreads();
#pragma unroll 8
    for (int k = 0; k < 64; ++k) {
      float4 a = *(const float4*)&As[k][ty * 4];
      float4 bv = *(const float4*)&Bs[k][tx * 4];
      acc[0][0] = fmaf(a.x, bv.x, acc[0][0]); acc[0][1] = fmaf(a.x, bv.y, acc[0][1]);
      acc[0][2] = fmaf(a.x, bv.z, acc[0][2]); acc[0][3] = fmaf(a.x, bv.w, acc[0][3]);
      acc[1][0] = fmaf(a.y, bv.x, acc[1][0]); acc[1][1] = fmaf(a.y, bv.y, acc[1][1]);
      acc[1][2] = fmaf(a.y, bv.z, acc[1][2]); acc[1][3] = fmaf(a.y, bv.w, acc[1][3]);
      acc[2][0] = fmaf(a.z, bv.x, acc[2][0]); acc[2][1] = fmaf(a.z, bv.y, acc[2][1]);
      acc[2][2] = fmaf(a.z, bv.z, acc[2][2]); acc[2][3] = fmaf(a.z, bv.w, acc[2][3]);
      acc[3][0] = fmaf(a.w, bv.x, acc[3][0]); acc[3][1] = fmaf(a.w, bv.y, acc[3][1]);
      acc[3][2] = fmaf(a.w, bv.z, acc[3][2]); acc[3][3] = fmaf(a.w, bv.w, acc[3][3]);
    }
  }
  float s[4], mm[4], be[4], bias[4];
#pragma unroll
  for (int jj = 0; jj < 4; ++jj) {
    int c = c0 + tx * 4 + jj;
    s[jj]    = bn1[c] / sqrtf(bn1[3 * Cc + c] + BN_EPS);
    mm[jj]   = bn1[2 * Cc + c];
    be[jj]   = bn1[Cc + c];
    bias[jj] = b1[c];
  }
#pragma unroll
  for (int ii = 0; ii < 4; ++ii) {
    int n = n0 + ty * 4 + ii;
    float4 o;
    o.x = (acc[ii][0] + bias[0] - mm[0]) * s[0] + be[0];
    o.y = (acc[ii][1] + bias[1] - mm[1]) * s[1] + be[1];
    o.z = (acc[ii][2] + bias[2] - mm[2]) * s[2] + be[2];
    o.w = (acc[ii][3] + bias[3] - mm[3]) * s[3] + be[3];
    *(float4*)&y[((size_t)b * NN + n) * Cc + c0 + tx * 4] = o;
  }
}

// ---------------------------------------------------------------- row sums of y^2 (UNCHANGED: bits feed topk)
__global__ __launch_bounds__(64) void k_sq(const float* __restrict__ y,
                                           float* __restrict__ sq) {
  int bn = blockIdx.x;
  int lane = threadIdx.x;
  const float* yp = y + (size_t)bn * Cc;
  float s = 0.f;
  for (int k = lane; k < Cc; k += 64) { float v = yp[k]; s = fmaf(v, v, s); }
#pragma unroll
  for (int off = 32; off; off >>= 1) s += __shfl_down(s, off);
  if (lane == 0) sq[bn] = s;
}

// ---------------------------------------------------------------- h = y @ Wg
// A[k][r] = y[r][k] (transpose-staged), B[k][c] = Wg[k][c] (direct)
__global__ __launch_bounds__(256) void k_hgemm(const float* __restrict__ y,
                                               const float* __restrict__ Wg,
                                               float* __restrict__ h) {
  int r0 = blockIdx.x * 64, c0 = blockIdx.y * 64;
  __shared__ float As[64][64];   // [k][row]
  __shared__ float Bs[64][64];   // [k][col]
  int t = threadIdx.x;
  int tx = t & 15, ty = t >> 4;
  float acc[4][4] = {};
  for (int k0 = 0; k0 < Cc; k0 += 64) {
    __syncthreads();
#pragma unroll
    for (int i = 0; i < 4; ++i) {
      int fi = t * 4 + i;
      int r = fi >> 4, q = fi & 15;
      float4 av = *(const float4*)&y[(size_t)(r0 + r) * Cc + k0 + q * 4];
      As[q * 4 + 0][r] = av.x; As[q * 4 + 1][r] = av.y;
      As[q * 4 + 2][r] = av.z; As[q * 4 + 3][r] = av.w;
      float4 bv = *(const float4*)&Wg[(size_t)(k0 + r) * FF + c0 + q * 4];
      *(float4*)&Bs[r][q * 4] = bv;
    }
    __syncthreads();
#pragma unroll 8
    for (int k = 0; k < 64; ++k) {
      float4 a = *(const float4*)&As[k][ty * 4];
      float4 bv = *(const float4*)&Bs[k][tx * 4];
      acc[0][0] = fmaf(a.x, bv.x, acc[0][0]); acc[0][1] = fmaf(a.x, bv.y, acc[0][1]);
      acc[0][2] = fmaf(a.x, bv.z, acc[0][2]); acc[0][3] = fmaf(a.x, bv.w, acc[0][3]);
      acc[1][0] = fmaf(a.y, bv.x, acc[1][0]); acc[1][1] = fmaf(a.y, bv.y, acc[1][1]);
      acc[1][2] = fmaf(a.y, bv.z, acc[1][2]); acc[1][3] = fmaf(a.y, bv.w, acc[1][3]);
      acc[2][0] = fmaf(a.z, bv.x, acc[2][0]); acc[2][1] = fmaf(a.z, bv.y, acc[2][1]);
      acc[2][2] = fmaf(a.z, bv.z, acc[2][2]); acc[2][3] = fmaf(a.z, bv.w, acc[2][3]);
      acc[3][0] = fmaf(a.w, bv.x, acc[3][0]); acc[3][1] = fmaf(a.w, bv.y, acc[3][1]);
      acc[3][2] = fmaf(a.w, bv.z, acc[3][2]); acc[3][3] = fmaf(a.w, bv.w, acc[3][3]);
    }
  }
#pragma unroll
  for (int ii = 0; ii < 4; ++ii) {
    int r = r0 + ty * 4 + ii;
    float4 o = {acc[ii][0], acc[ii][1], acc[ii][2], acc[ii][3]};
    *(float4*)&h[(size_t)r * FF + c0 + tx * 4] = o;
  }
}

// ---------------------------------------------------------------- a_src / a_dst (UNCHANGED)
__global__ __launch_bounds__(256) void k_attn_coef(
    const float* __restrict__ h, const float* __restrict__ att_src,
    const float* __restrict__ att_dst, float* __restrict__ asrc,
    float* __restrict__ adst) {
  int bn = blockIdx.x;
  int head = threadIdx.x / 64, lane = threadIdx.x % 64;
  const float* hp = h + (size_t)bn * FF + head * HD;
  const float* as = att_src + head * HD;
  const float* ad = att_dst + head * HD;
  float s1 = 0.f, s2 = 0.f;
  for (int d = lane; d < HD; d += 64) {
    float v = hp[d];
    s1 = fmaf(v, as[d], s1);
    s2 = fmaf(v, ad[d], s2);
  }
#pragma unroll
  for (int off = 32; off; off >>= 1) {
    s1 += __shfl_down(s1, off);
    s2 += __shfl_down(s2, off);
  }
  if (lane == 0) {
    asrc[bn * NH + head] = s1;
    adst[bn * NH + head] = s2;
  }
}

// ---------------------------------------------------------------- pairwise distances (same fma order as R0)
__global__ __launch_bounds__(256) void k_dist(const float* __restrict__ y,
                                              const float* __restrict__ sq,
                                              float* __restrict__ dist) {
  int b = blockIdx.z, nt = blockIdx.y, mt = blockIdx.x;
  int n0 = nt * 64, m0 = mt * 64;
  __shared__ float As[64][64];   // [k][n]
  __shared__ float Bs[64][64];   // [k][m]
  const float* yb = y + (size_t)b * NN * Cc;
  int t = threadIdx.x;
  int tx = t & 15, ty = t >> 4;
  float acc[4][4] = {};
  for (int k0 = 0; k0 < Cc; k0 += 64) {
    __syncthreads();
#pragma unroll
    for (int i = 0; i < 4; ++i) {
      int fi = t * 4 + i;
      int r = fi >> 4, q = fi & 15;
      float4 av = *(const float4*)&yb[(size_t)(n0 + r) * Cc + k0 + q * 4];
      As[q * 4 + 0][r] = av.x; As[q * 4 + 1][r] = av.y;
      As[q * 4 + 2][r] = av.z; As[q * 4 + 3][r] = av.w;
      float4 bv = *(const float4*)&yb[(size_t)(m0 + r) * Cc + k0 + q * 4];
      Bs[q * 4 + 0][r] = bv.x; Bs[q * 4 + 1][r] = bv.y;
      Bs[q * 4 + 2][r] = bv.z; Bs[q * 4 + 3][r] = bv.w;
    }
    __syncthreads();
#pragma unroll 8
    for (int k = 0; k < 64; ++k) {
      float4 a = *(const float4*)&As[k][ty * 4];
      float4 bv = *(const float4*)&Bs[k][tx * 4];
      acc[0][0] = fmaf(a.x, bv.x, acc[0][0]); acc[0][1] = fmaf(a.x, bv.y, acc[0][1]);
      acc[0][2] = fmaf(a.x, bv.z, acc[0][2]); acc[0][3] = fmaf(a.x, bv.w, acc[0][3]);
      acc[1][0] = fmaf(a.y, bv.x, acc[1][0]); acc[1][1] = fmaf(a.y, bv.y, acc[1][1]);
      acc[1][2] = fmaf(a.y, bv.z, acc[1][2]); acc[1][3] = fmaf(a.y, bv.w, acc[1][3]);
      acc[2][0] = fmaf(a.z, bv.x, acc[2][0]); acc[2][1] = fmaf(a.z, bv.y, acc[2][1]);
      acc[2][2] = fmaf(a.z, bv.z, acc[2][2]); acc[2][3] = fmaf(a.z, bv.w, acc[2][3]);
      acc[3][0] = fmaf(a.w, bv.x, acc[3][0]); acc[3][1] = fmaf(a.w, bv.y, acc[3][1]);
      acc[3][2] = fmaf(a.w, bv.z, acc[3][2]); acc[3][3] = fmaf(a.w, bv.w, acc[3][3]);
    }
  }
#pragma unroll
  for (int ii = 0; ii < 4; ++ii) {
    int n = n0 + ty * 4 + ii;
    float sn = sq[b * NN + n];
    float4 o;
    o.x = sn + sq[b * NN + m0 + tx * 4 + 0] - 2.f * acc[ii][0];
    o.y = sn + sq[b * NN + m0 + tx * 4 + 1] - 2.f * acc[ii][1];
    o.z = sn + sq[b * NN + m0 + tx * 4 + 2] - 2.f * acc[ii][2];
    o.w = sn + sq[b * NN + m0 + tx * 4 + 3] - 2.f * acc[ii][3];
    *(float4*)&dist[((size_t)b * NN + n) * NN + m0 + tx * 4] = o;
  }
}

// ---------------------------------------------------------------- top-16 smallest per row (float4 loads)
__global__ __launch_bounds__(64) void k_topk(const float* __restrict__ dist,
                                             int* __restrict__ idx) {
  int bn = blockIdx.x;
  int lane = threadIdx.x;
  const float4* dp = (const float4*)(dist + (size_t)bn * NN);
  float dv[16];
#pragma unroll
  for (int q = 0; q < 4; ++q) {
    float4 v = dp[lane + 64 * q];
    dv[q * 4 + 0] = v.x; dv[q * 4 + 1] = v.y;
    dv[q * 4 + 2] = v.z; dv[q * 4 + 3] = v.w;
  }
  for (int sel = 0; sel < KN; ++sel) {
    float bv = INFINITY;
    int bi = 0x7fffffff;
#pragma unroll
    for (int q = 0; q < 4; ++q)
#pragma unroll
      for (int j = 0; j < 4; ++j) {
        int m = (lane + 64 * q) * 4 + j;
        float v = dv[q * 4 + j];
        if (v < bv || (v == bv && m < bi)) { bv = v; bi = m; }
      }
#pragma unroll
    for (int off = 32; off; off >>= 1) {
      float ov = __shfl_xor(bv, off);
      int oi   = __shfl_xor(bi, off);
      if (ov < bv || (ov == bv && oi < bi)) { bv = ov; bi = oi; }
    }
    if (lane == 0) idx[bn * KN + sel] = bi;
#pragma unroll
    for (int q = 0; q < 4; ++q)
#pragma unroll
      for (int j = 0; j < 4; ++j)
        if ((lane + 64 * q) * 4 + j == bi) dv[q * 4 + j] = INFINITY;
  }
}

// ---------------------------------------------------------------- GAT aggregate + BN + GELU (float4 gather)
__global__ __launch_bounds__(128) void k_gat(
    const float* __restrict__ h, const float* __restrict__ asrc,
    const float* __restrict__ adst, const int* __restrict__ idx,
    const float* __restrict__ bg, const float* __restrict__ bng,
    float* __restrict__ g) {
  int bn = blockIdx.x;
  int b = bn / NN;
  __shared__ int nb[KN];
  __shared__ float attn[KN][NH];
  int t = threadIdx.x;
  if (t < KN) nb[t] = idx[bn * KN + t];
  __syncthreads();
  if (t < KN * NH) {
    int k = t % KN, hd = t / KN;
    float e = asrc[((size_t)b * NN + nb[k]) * NH + hd] +
              adst[(size_t)bn * NH + hd];
    e = (e >= 0.f) ? e : 0.2f * e;
    attn[k][hd] = e;
  }
  __syncthreads();
  if (t < NH) {
    float mx = -INFINITY;
    for (int k = 0; k < KN; ++k) mx = fmaxf(mx, attn[k][t]);
    float s = 0.f;
    for (int k = 0; k < KN; ++k) {
      float ev = expf(attn[k][t] - mx);
      attn[k][t] = ev;
      s += ev;
    }
    float inv = 1.f / s;
    for (int k = 0; k < KN; ++k) attn[k][t] *= inv;
  }
  __syncthreads();
  if (t < 96) {
    int d = t * 4;
    float4 acc = {0.f, 0.f, 0.f, 0.f};
    for (int k = 0; k < KN; ++k) {
      const float* hp = h + ((size_t)b * NN + nb[k]) * FF + d;
      float4 aw = *(const float4*)&attn[k][0];
      float4 h0 = *(const float4*)&hp[0];
      float4 h1 = *(const float4*)&hp[HD];
      float4 h2 = *(const float4*)&hp[2 * HD];
      float4 h3 = *(const float4*)&hp[3 * HD];
      // per output element: hh ascending (same fma order as R0)
      acc.x = fmaf(aw.x, h0.x, acc.x); acc.x = fmaf(aw.y, h1.x, acc.x);
      acc.x = fmaf(aw.z, h2.x, acc.x); acc.x = fmaf(aw.w, h3.x, acc.x);
      acc.y = fmaf(aw.x, h0.y, acc.y); acc.y = fmaf(aw.y, h1.y, acc.y);
      acc.y = fmaf(aw.z, h2.y, acc.y); acc.y = fmaf(aw.w, h3.y, acc.y);
      acc.z = fmaf(aw.x, h0.z, acc.z); acc.z = fmaf(aw.y, h1.z, acc.z);
      acc.z = fmaf(aw.z, h2.z, acc.z); acc.z = fmaf(aw.w, h3.z, acc.z);
      acc.w = fmaf(aw.x, h0.w, acc.w); acc.w = fmaf(aw.y, h1.w, acc.w);
      acc.w = fmaf(aw.z, h2.w, acc.w); acc.w = fmaf(aw.w, h3.w, acc.w);
    }
    float o[4] = {acc.x, acc.y, acc.z, acc.w};
    float4 r;
    float* rp = (float*)&r;
#pragma unroll
    for (int j = 0; j < 4; ++j) {
      int dd = d + j;
      float val = o[j] * 0.25f + bg[dd];
      float sc = bng[dd] / sqrtf(bng[3 * HD + dd] + BN_EPS);
      val = (val - bng[2 * HD + dd]) * sc + bng[HD + dd];
      val = 0.5f * val * (1.f + erff(val * 0.7071067811865475f));
      rp[j] = val;
    }
    *(float4*)&g[(size_t)bn * HD + d] = r;
  }
}

// ---------------------------------------------------------------- fc2 + BN + residual + transpose
// A[k][n] = g[n][k] (transpose-staged), B[k][c] = W2[c][k] (transpose-staged)
__global__ __launch_bounds__(256) void k_fc2(
    const float* __restrict__ g, const float* __restrict__ W2,
    const float* __restrict__ b2, const float* __restrict__ bn2,
    const float* __restrict__ x, float* __restrict__ out) {
  int nt = blockIdx.x, ct = blockIdx.y, b = blockIdx.z;
  int n0 = nt * 64, c0 = ct * 64;
  __shared__ float As[64][64];   // [k][n]
  __shared__ float Bs[64][64];   // [k][c]
  int t = threadIdx.x;
  int tx = t & 15, ty = t >> 4;
  float acc[4][4] = {};
  for (int k0 = 0; k0 < HD; k0 += 64) {
    __syncthreads();
#pragma unroll
    for (int i = 0; i < 4; ++i) {
      int fi = t * 4 + i;
      int r = fi >> 4, q = fi & 15;
      float4 av = *(const float4*)&g[((size_t)b * NN + n0 + r) * HD + k0 + q * 4];
      As[q * 4 + 0][r] = av.x; As[q * 4 + 1][r] = av.y;
      As[q * 4 + 2][r] = av.z; As[q * 4 + 3][r] = av.w;
      float4 bv = *(const float4*)&W2[(size_t)(c0 + r) * HD + k0 + q * 4];
      Bs[q * 4 + 0][r] = bv.x; Bs[q * 4 + 1][r] = bv.y;
      Bs[q * 4 + 2][r] = bv.z; Bs[q * 4 + 3][r] = bv.w;
    }
    __syncthreads();
#pragma unroll 8
    for (int k = 0; k < 64; ++k) {
      float4 a = *(const float4*)&As[k][ty * 4];
      float4 bv = *(const float4*)&Bs[k][tx * 4];
      acc[0][0] = fmaf(a.x, bv.x, acc[0][0]); acc[0][1] = fmaf(a.x, bv.y, acc[0][1]);
      acc[0][2] = fmaf(a.x, bv.z, acc[0][2]); acc[0][3] = fmaf(a.x, bv.w, acc[0][3]);
      acc[1][0] = fmaf(a.y, bv.x, acc[1][0]); acc[1][1] = fmaf(a.y, bv.y, acc[1][1]);
      acc[1][2] = fmaf(a.y, bv.z, acc[1][2]); acc[1][3] = fmaf(a.y, bv.w, acc[1][3]);
      acc[2][0] = fmaf(a.z, bv.x, acc[2][0]); acc[2][1] = fmaf(a.z, bv.y, acc[2][1]);
      acc[2][2] = fmaf(a.z, bv.z, acc[2][2]); acc[2][3] = fmaf(a.z, bv.w, acc[2][3]);
      acc[3][0] = fmaf(a.w, bv.x, acc[3][0]); acc[3][1] = fmaf(a.w, bv.y, acc[3][1]);
      acc[3][2] = fmaf(a.w, bv.z, acc[3][2]); acc[3][3] = fmaf(a.w, bv.w, acc[3][3]);
    }
  }
#pragma unroll
  for (int jj = 0; jj < 4; ++jj) {
    int c = c0 + tx * 4 + jj;
    float s  = bn2[c] / sqrtf(bn2[3 * Cc + c] + BN_EPS);
    float mm = bn2[2 * Cc + c];
    float be = bn2[Cc + c];
    float bias = b2[c];
    float4 res = *(const float4*)&x[((size_t)b * Cc + c) * NN + n0 + ty * 4];
    float4 o;
    o.x = (acc[0][jj] + bias - mm) * s + be + res.x;
    o.y = (acc[1][jj] + bias - mm) * s + be + res.y;
    o.z = (acc[2][jj] + bias - mm) * s + be + res.z;
    o.w = (acc[3][jj] + bias - mm) * s + be + res.w;
    *(float4*)&out[((size_t)b * Cc + c) * NN + n0 + ty * 4] = o;
  }
}

extern "C" void kernel_launch(void* const* d_in, const int* in_sizes, int n_in,
                              void* d_out, int out_size, void* d_ws, size_t ws_size,
                              hipStream_t stream) {
  const float* x       = (const float*)d_in[0];
  const float* W1      = (const float*)d_in[1];
  const float* b1      = (const float*)d_in[2];
  const float* bn1     = (const float*)d_in[3];
  const float* Wg      = (const float*)d_in[4];
  const float* att_src = (const float*)d_in[5];
  const float* att_dst = (const float*)d_in[6];
  const float* bg      = (const float*)d_in[7];
  const float* bng     = (const float*)d_in[8];
  const float* W2      = (const float*)d_in[9];
  const float* b2      = (const float*)d_in[10];
  const float* bn2     = (const float*)d_in[11];
  float* out = (float*)d_out;

  float* ws   = (float*)d_ws;
  float* y    = ws;                        // 786432
  float* h    = y + 786432;                // 6291456
  float* sq   = h + 6291456;               // 4096
  float* asrc = sq + 4096;                 // 16384
  float* adst = asrc + 16384;              // 16384
  float* dist = adst + 16384;              // 4194304
  float* g    = dist;                      // 1572864 (reuse; dist dead after topk)
  int*   idx  = (int*)(dist + 4194304);    // 65536 ints

  k_fc1<<<dim3(16, 3, 4), 256, 0, stream>>>(x, W1, b1, bn1, y);
  k_sq<<<Bb * NN, 64, 0, stream>>>(y, sq);
  k_hgemm<<<dim3(64, 24), 256, 0, stream>>>(y, Wg, h);
  k_attn_coef<<<Bb * NN, 256, 0, stream>>>(h, att_src, att_dst, asrc, adst);
  k_dist<<<dim3(16, 16, 4), 256, 0, stream>>>(y, sq, dist);
  k_topk<<<Bb * NN, 64, 0, stream>>>(dist, idx);
  k_gat<<<Bb * NN, 128, 0, stream>>>(h, asrc, adst, idx, bg, bng, g);
  k_fc2<<<dim3(16, 3, 4), 256, 0, stream>>>(g, W2, b2, bn2, x, out);
}

// Round 3
// 168.914 us; speedup vs baseline: 1.4259x; 1.1324x over previous
//
#include <hip/hip_runtime.h>
#include <math.h>

#define Bb 4
#define Cc 192
#define NN 1024
#define HD 384
#define NH 4
#define FF 1536   // NH*HD
#define KN 16
#define BN_EPS 1e-5f

// ---------------------------------------------------------------- fc1 + BN
// y[b,n,c] = BN1( sum_k x[b,k,n]*W1[c,k] + b1[c] )
// A[k][n] = x[b][k][n] (direct, k-major already), B[k][c] = W1[c][k] (transpose-staged)
__global__ __launch_bounds__(256) void k_fc1(
    const float* __restrict__ x, const float* __restrict__ W1,
    const float* __restrict__ b1, const float* __restrict__ bn1,
    float* __restrict__ y) {
  int nt = blockIdx.x, ct = blockIdx.y, b = blockIdx.z;
  int n0 = nt * 64, c0 = ct * 64;
  __shared__ float As[64][64];   // [k][n]
  __shared__ float Bs[64][64];   // [k][c]
  int t = threadIdx.x;
  int tx = t & 15, ty = t >> 4;
  float acc[4][4] = {};
  for (int k0 = 0; k0 < Cc; k0 += 64) {
    __syncthreads();
#pragma unroll
    for (int i = 0; i < 4; ++i) {
      int fi = t * 4 + i;
      int r = fi >> 4, q = fi & 15;
      float4 av = *(const float4*)&x[((size_t)b * Cc + k0 + r) * NN + n0 + q * 4];
      *(float4*)&As[r][q * 4] = av;
      float4 bv = *(const float4*)&W1[(size_t)(c0 + r) * Cc + k0 + q * 4];
      Bs[q * 4 + 0][r] = bv.x; Bs[q * 4 + 1][r] = bv.y;
      Bs[q * 4 + 2][r] = bv.z; Bs[q * 4 + 3][r] = bv.w;
    }
    __syncthreads();
#pragma unroll 8
    for (int k = 0; k < 64; ++k) {
      float4 a = *(const float4*)&As[k][ty * 4];
      float4 bv = *(const float4*)&Bs[k][tx * 4];
      acc[0][0] = fmaf(a.x, bv.x, acc[0][0]); acc[0][1] = fmaf(a.x, bv.y, acc[0][1]);
      acc[0][2] = fmaf(a.x, bv.z, acc[0][2]); acc[0][3] = fmaf(a.x, bv.w, acc[0][3]);
      acc[1][0] = fmaf(a.y, bv.x, acc[1][0]); acc[1][1] = fmaf(a.y, bv.y, acc[1][1]);
      acc[1][2] = fmaf(a.y, bv.z, acc[1][2]); acc[1][3] = fmaf(a.y, bv.w, acc[1][3]);
      acc[2][0] = fmaf(a.z, bv.x, acc[2][0]); acc[2][1] = fmaf(a.z, bv.y, acc[2][1]);
      acc[2][2] = fmaf(a.z, bv.z, acc[2][2]); acc[2][3] = fmaf(a.z, bv.w, acc[2][3]);
      acc[3][0] = fmaf(a.w, bv.x, acc[3][0]); acc[3][1] = fmaf(a.w, bv.y, acc[3][1]);
      acc[3][2] = fmaf(a.w, bv.z, acc[3][2]); acc[3][3] = fmaf(a.w, bv.w, acc[3][3]);
    }
  }
  float s[4], mm[4], be[4], bias[4];
#pragma unroll
  for (int jj = 0; jj < 4; ++jj) {
    int c = c0 + tx * 4 + jj;
    s[jj]    = bn1[c] / sqrtf(bn1[3 * Cc + c] + BN_EPS);
    mm[jj]   = bn1[2 * Cc + c];
    be[jj]   = bn1[Cc + c];
    bias[jj] = b1[c];
  }
#pragma unroll
  for (int ii = 0; ii < 4; ++ii) {
    int n = n0 + ty * 4 + ii;
    float4 o;
    o.x = (acc[ii][0] + bias[0] - mm[0]) * s[0] + be[0];
    o.y = (acc[ii][1] + bias[1] - mm[1]) * s[1] + be[1];
    o.z = (acc[ii][2] + bias[2] - mm[2]) * s[2] + be[2];
    o.w = (acc[ii][3] + bias[3] - mm[3]) * s[3] + be[3];
    *(float4*)&y[((size_t)b * NN + n) * Cc + c0 + tx * 4] = o;
  }
}

// ---------------------------------------------------------------- row sums of y^2 (UNCHANGED: bits feed topk)
__global__ __launch_bounds__(64) void k_sq(const float* __restrict__ y,
                                           float* __restrict__ sq) {
  int bn = blockIdx.x;
  int lane = threadIdx.x;
  const float* yp = y + (size_t)bn * Cc;
  float s = 0.f;
  for (int k = lane; k < Cc; k += 64) { float v = yp[k]; s = fmaf(v, v, s); }
#pragma unroll
  for (int off = 32; off; off >>= 1) s += __shfl_down(s, off);
  if (lane == 0) sq[bn] = s;
}

// ---------------------------------------------------------------- h = y @ Wg
__global__ __launch_bounds__(256) void k_hgemm(const float* __restrict__ y,
                                               const float* __restrict__ Wg,
                                               float* __restrict__ h) {
  int r0 = blockIdx.x * 64, c0 = blockIdx.y * 64;
  __shared__ float As[64][64];   // [k][row]
  __shared__ float Bs[64][64];   // [k][col]
  int t = threadIdx.x;
  int tx = t & 15, ty = t >> 4;
  float acc[4][4] = {};
  for (int k0 = 0; k0 < Cc; k0 += 64) {
    __syncthreads();
#pragma unroll
    for (int i = 0; i < 4; ++i) {
      int fi = t * 4 + i;
      int r = fi >> 4, q = fi & 15;
      float4 av = *(const float4*)&y[(size_t)(r0 + r) * Cc + k0 + q * 4];
      As[q * 4 + 0][r] = av.x; As[q * 4 + 1][r] = av.y;
      As[q * 4 + 2][r] = av.z; As[q * 4 + 3][r] = av.w;
      float4 bv = *(const float4*)&Wg[(size_t)(k0 + r) * FF + c0 + q * 4];
      *(float4*)&Bs[r][q * 4] = bv;
    }
    __syncthreads();
#pragma unroll 8
    for (int k = 0; k < 64; ++k) {
      float4 a = *(const float4*)&As[k][ty * 4];
      float4 bv = *(const float4*)&Bs[k][tx * 4];
      acc[0][0] = fmaf(a.x, bv.x, acc[0][0]); acc[0][1] = fmaf(a.x, bv.y, acc[0][1]);
      acc[0][2] = fmaf(a.x, bv.z, acc[0][2]); acc[0][3] = fmaf(a.x, bv.w, acc[0][3]);
      acc[1][0] = fmaf(a.y, bv.x, acc[1][0]); acc[1][1] = fmaf(a.y, bv.y, acc[1][1]);
      acc[1][2] = fmaf(a.y, bv.z, acc[1][2]); acc[1][3] = fmaf(a.y, bv.w, acc[1][3]);
      acc[2][0] = fmaf(a.z, bv.x, acc[2][0]); acc[2][1] = fmaf(a.z, bv.y, acc[2][1]);
      acc[2][2] = fmaf(a.z, bv.z, acc[2][2]); acc[2][3] = fmaf(a.z, bv.w, acc[2][3]);
      acc[3][0] = fmaf(a.w, bv.x, acc[3][0]); acc[3][1] = fmaf(a.w, bv.y, acc[3][1]);
      acc[3][2] = fmaf(a.w, bv.z, acc[3][2]); acc[3][3] = fmaf(a.w, bv.w, acc[3][3]);
    }
  }
#pragma unroll
  for (int ii = 0; ii < 4; ++ii) {
    int r = r0 + ty * 4 + ii;
    float4 o = {acc[ii][0], acc[ii][1], acc[ii][2], acc[ii][3]};
    *(float4*)&h[(size_t)r * FF + c0 + tx * 4] = o;
  }
}

// ---------------------------------------------------------------- a_src / a_dst (UNCHANGED)
__global__ __launch_bounds__(256) void k_attn_coef(
    const float* __restrict__ h, const float* __restrict__ att_src,
    const float* __restrict__ att_dst, float* __restrict__ asrc,
    float* __restrict__ adst) {
  int bn = blockIdx.x;
  int head = threadIdx.x / 64, lane = threadIdx.x % 64;
  const float* hp = h + (size_t)bn * FF + head * HD;
  const float* as = att_src + head * HD;
  const float* ad = att_dst + head * HD;
  float s1 = 0.f, s2 = 0.f;
  for (int d = lane; d < HD; d += 64) {
    float v = hp[d];
    s1 = fmaf(v, as[d], s1);
    s2 = fmaf(v, ad[d], s2);
  }
#pragma unroll
  for (int off = 32; off; off >>= 1) {
    s1 += __shfl_down(s1, off);
    s2 += __shfl_down(s2, off);
  }
  if (lane == 0) {
    asrc[bn * NH + head] = s1;
    adst[bn * NH + head] = s2;
  }
}

// ---------------------------------------------------------------- pairwise distances (same fma order as R0)
__global__ __launch_bounds__(256) void k_dist(const float* __restrict__ y,
                                              const float* __restrict__ sq,
                                              float* __restrict__ dist) {
  int b = blockIdx.z, nt = blockIdx.y, mt = blockIdx.x;
  int n0 = nt * 64, m0 = mt * 64;
  __shared__ float As[64][64];   // [k][n]
  __shared__ float Bs[64][64];   // [k][m]
  const float* yb = y + (size_t)b * NN * Cc;
  int t = threadIdx.x;
  int tx = t & 15, ty = t >> 4;
  float acc[4][4] = {};
  for (int k0 = 0; k0 < Cc; k0 += 64) {
    __syncthreads();
#pragma unroll
    for (int i = 0; i < 4; ++i) {
      int fi = t * 4 + i;
      int r = fi >> 4, q = fi & 15;
      float4 av = *(const float4*)&yb[(size_t)(n0 + r) * Cc + k0 + q * 4];
      As[q * 4 + 0][r] = av.x; As[q * 4 + 1][r] = av.y;
      As[q * 4 + 2][r] = av.z; As[q * 4 + 3][r] = av.w;
      float4 bv = *(const float4*)&yb[(size_t)(m0 + r) * Cc + k0 + q * 4];
      Bs[q * 4 + 0][r] = bv.x; Bs[q * 4 + 1][r] = bv.y;
      Bs[q * 4 + 2][r] = bv.z; Bs[q * 4 + 3][r] = bv.w;
    }
    __syncthreads();
#pragma unroll 8
    for (int k = 0; k < 64; ++k) {
      float4 a = *(const float4*)&As[k][ty * 4];
      float4 bv = *(const float4*)&Bs[k][tx * 4];
      acc[0][0] = fmaf(a.x, bv.x, acc[0][0]); acc[0][1] = fmaf(a.x, bv.y, acc[0][1]);
      acc[0][2] = fmaf(a.x, bv.z, acc[0][2]); acc[0][3] = fmaf(a.x, bv.w, acc[0][3]);
      acc[1][0] = fmaf(a.y, bv.x, acc[1][0]); acc[1][1] = fmaf(a.y, bv.y, acc[1][1]);
      acc[1][2] = fmaf(a.y, bv.z, acc[1][2]); acc[1][3] = fmaf(a.y, bv.w, acc[1][3]);
      acc[2][0] = fmaf(a.z, bv.x, acc[2][0]); acc[2][1] = fmaf(a.z, bv.y, acc[2][1]);
      acc[2][2] = fmaf(a.z, bv.z, acc[2][2]); acc[2][3] = fmaf(a.z, bv.w, acc[2][3]);
      acc[3][0] = fmaf(a.w, bv.x, acc[3][0]); acc[3][1] = fmaf(a.w, bv.y, acc[3][1]);
      acc[3][2] = fmaf(a.w, bv.z, acc[3][2]); acc[3][3] = fmaf(a.w, bv.w, acc[3][3]);
    }
  }
#pragma unroll
  for (int ii = 0; ii < 4; ++ii) {
    int n = n0 + ty * 4 + ii;
    float sn = sq[b * NN + n];
    float4 o;
    o.x = sn + sq[b * NN + m0 + tx * 4 + 0] - 2.f * acc[ii][0];
    o.y = sn + sq[b * NN + m0 + tx * 4 + 1] - 2.f * acc[ii][1];
    o.z = sn + sq[b * NN + m0 + tx * 4 + 2] - 2.f * acc[ii][2];
    o.w = sn + sq[b * NN + m0 + tx * 4 + 3] - 2.f * acc[ii][3];
    *(float4*)&dist[((size_t)b * NN + n) * NN + m0 + tx * 4] = o;
  }
}

// ---------------------------------------------------------------- top-16 smallest per row (float4 loads)
__global__ __launch_bounds__(64) void k_topk(const float* __restrict__ dist,
                                             int* __restrict__ idx) {
  int bn = blockIdx.x;
  int lane = threadIdx.x;
  const float4* dp = (const float4*)(dist + (size_t)bn * NN);
  float dv[16];
#pragma unroll
  for (int q = 0; q < 4; ++q) {
    float4 v = dp[lane + 64 * q];
    dv[q * 4 + 0] = v.x; dv[q * 4 + 1] = v.y;
    dv[q * 4 + 2] = v.z; dv[q * 4 + 3] = v.w;
  }
  for (int sel = 0; sel < KN; ++sel) {
    float bv = INFINITY;
    int bi = 0x7fffffff;
#pragma unroll
    for (int q = 0; q < 4; ++q)
#pragma unroll
      for (int j = 0; j < 4; ++j) {
        int m = (lane + 64 * q) * 4 + j;
        float v = dv[q * 4 + j];
        if (v < bv || (v == bv && m < bi)) { bv = v; bi = m; }
      }
#pragma unroll
    for (int off = 32; off; off >>= 1) {
      float ov = __shfl_xor(bv, off);
      int oi   = __shfl_xor(bi, off);
      if (ov < bv || (ov == bv && oi < bi)) { bv = ov; bi = oi; }
    }
    if (lane == 0) idx[bn * KN + sel] = bi;
#pragma unroll
    for (int q = 0; q < 4; ++q)
#pragma unroll
      for (int j = 0; j < 4; ++j)
        if ((lane + 64 * q) * 4 + j == bi) dv[q * 4 + j] = INFINITY;
  }
}

// ---------------------------------------------------------------- GAT aggregate + BN + GELU
// launch_bounds(128,4): force VGPR<=128 -> 16 waves/CU (2x concurrency for the
// latency-bound gather). XCD swizzle: 512 consecutive nodes per XCD -> their
// neighbors' h rows (~3MB) fit the 4MB per-XCD L2.
__global__ __launch_bounds__(128, 4) void k_gat(
    const float* __restrict__ h, const float* __restrict__ asrc,
    const float* __restrict__ adst, const int* __restrict__ idx,
    const float* __restrict__ bg, const float* __restrict__ bng,
    float* __restrict__ g) {
  int bid = blockIdx.x;
  int bn = (bid & 7) * (Bb * NN / 8) + (bid >> 3);   // bijective XCD swizzle (4096 % 8 == 0)
  int b = bn / NN;
  __shared__ int nb[KN];
  __shared__ float attn[KN][NH];
  int t = threadIdx.x;
  if (t < KN) nb[t] = idx[bn * KN + t];
  __syncthreads();
  if (t < KN * NH) {
    int k = t % KN, hd = t / KN;
    float e = asrc[((size_t)b * NN + nb[k]) * NH + hd] +
              adst[(size_t)bn * NH + hd];
    e = (e >= 0.f) ? e : 0.2f * e;
    attn[k][hd] = e;
  }
  __syncthreads();
  if (t < NH) {
    float mx = -INFINITY;
    for (int k = 0; k < KN; ++k) mx = fmaxf(mx, attn[k][t]);
    float s = 0.f;
    for (int k = 0; k < KN; ++k) {
      float ev = expf(attn[k][t] - mx);
      attn[k][t] = ev;
      s += ev;
    }
    float inv = 1.f / s;
    for (int k = 0; k < KN; ++k) attn[k][t] *= inv;
  }
  __syncthreads();
  if (t < 96) {
    int d = t * 4;
    float4 acc = {0.f, 0.f, 0.f, 0.f};
#pragma unroll 4
    for (int k = 0; k < KN; ++k) {
      const float* hp = h + ((size_t)b * NN + nb[k]) * FF + d;
      float4 aw = *(const float4*)&attn[k][0];
      float4 h0 = *(const float4*)&hp[0];
      float4 h1 = *(const float4*)&hp[HD];
      float4 h2 = *(const float4*)&hp[2 * HD];
      float4 h3 = *(const float4*)&hp[3 * HD];
      acc.x = fmaf(aw.x, h0.x, acc.x); acc.x = fmaf(aw.y, h1.x, acc.x);
      acc.x = fmaf(aw.z, h2.x, acc.x); acc.x = fmaf(aw.w, h3.x, acc.x);
      acc.y = fmaf(aw.x, h0.y, acc.y); acc.y = fmaf(aw.y, h1.y, acc.y);
      acc.y = fmaf(aw.z, h2.y, acc.y); acc.y = fmaf(aw.w, h3.y, acc.y);
      acc.z = fmaf(aw.x, h0.z, acc.z); acc.z = fmaf(aw.y, h1.z, acc.z);
      acc.z = fmaf(aw.z, h2.z, acc.z); acc.z = fmaf(aw.w, h3.z, acc.z);
      acc.w = fmaf(aw.x, h0.w, acc.w); acc.w = fmaf(aw.y, h1.w, acc.w);
      acc.w = fmaf(aw.z, h2.w, acc.w); acc.w = fmaf(aw.w, h3.w, acc.w);
    }
    float o[4] = {acc.x, acc.y, acc.z, acc.w};
    float4 r;
    float* rp = (float*)&r;
#pragma unroll
    for (int j = 0; j < 4; ++j) {
      int dd = d + j;
      float val = o[j] * 0.25f + bg[dd];
      float sc = bng[dd] / sqrtf(bng[3 * HD + dd] + BN_EPS);
      val = (val - bng[2 * HD + dd]) * sc + bng[HD + dd];
      val = 0.5f * val * (1.f + erff(val * 0.7071067811865475f));
      rp[j] = val;
    }
    *(float4*)&g[(size_t)bn * HD + d] = r;
  }
}

// ---------------------------------------------------------------- fc2 + BN + residual + transpose
__global__ __launch_bounds__(256) void k_fc2(
    const float* __restrict__ g, const float* __restrict__ W2,
    const float* __restrict__ b2, const float* __restrict__ bn2,
    const float* __restrict__ x, float* __restrict__ out) {
  int nt = blockIdx.x, ct = blockIdx.y, b = blockIdx.z;
  int n0 = nt * 64, c0 = ct * 64;
  __shared__ float As[64][64];   // [k][n]
  __shared__ float Bs[64][64];   // [k][c]
  int t = threadIdx.x;
  int tx = t & 15, ty = t >> 4;
  float acc[4][4] = {};
  for (int k0 = 0; k0 < HD; k0 += 64) {
    __syncthreads();
#pragma unroll
    for (int i = 0; i < 4; ++i) {
      int fi = t * 4 + i;
      int r = fi >> 4, q = fi & 15;
      float4 av = *(const float4*)&g[((size_t)b * NN + n0 + r) * HD + k0 + q * 4];
      As[q * 4 + 0][r] = av.x; As[q * 4 + 1][r] = av.y;
      As[q * 4 + 2][r] = av.z; As[q * 4 + 3][r] = av.w;
      float4 bv = *(const float4*)&W2[(size_t)(c0 + r) * HD + k0 + q * 4];
      Bs[q * 4 + 0][r] = bv.x; Bs[q * 4 + 1][r] = bv.y;
      Bs[q * 4 + 2][r] = bv.z; Bs[q * 4 + 3][r] = bv.w;
    }
    __syncthreads();
#pragma unroll 8
    for (int k = 0; k < 64; ++k) {
      float4 a = *(const float4*)&As[k][ty * 4];
      float4 bv = *(const float4*)&Bs[k][tx * 4];
      acc[0][0] = fmaf(a.x, bv.x, acc[0][0]); acc[0][1] = fmaf(a.x, bv.y, acc[0][1]);
      acc[0][2] = fmaf(a.x, bv.z, acc[0][2]); acc[0][3] = fmaf(a.x, bv.w, acc[0][3]);
      acc[1][0] = fmaf(a.y, bv.x, acc[1][0]); acc[1][1] = fmaf(a.y, bv.y, acc[1][1]);
      acc[1][2] = fmaf(a.y, bv.z, acc[1][2]); acc[1][3] = fmaf(a.y, bv.w, acc[1][3]);
      acc[2][0] = fmaf(a.z, bv.x, acc[2][0]); acc[2][1] = fmaf(a.z, bv.y, acc[2][1]);
      acc[2][2] = fmaf(a.z, bv.z, acc[2][2]); acc[2][3] = fmaf(a.z, bv.w, acc[2][3]);
      acc[3][0] = fmaf(a.w, bv.x, acc[3][0]); acc[3][1] = fmaf(a.w, bv.y, acc[3][1]);
      acc[3][2] = fmaf(a.w, bv.z, acc[3][2]); acc[3][3] = fmaf(a.w, bv.w, acc[3][3]);
    }
  }
#pragma unroll
  for (int jj = 0; jj < 4; ++jj) {
    int c = c0 + tx * 4 + jj;
    float s  = bn2[c] / sqrtf(bn2[3 * Cc + c] + BN_EPS);
    float mm = bn2[2 * Cc + c];
    float be = bn2[Cc + c];
    float bias = b2[c];
    float4 res = *(const float4*)&x[((size_t)b * Cc + c) * NN + n0 + ty * 4];
    float4 o;
    o.x = (acc[0][jj] + bias - mm) * s + be + res.x;
    o.y = (acc[1][jj] + bias - mm) * s + be + res.y;
    o.z = (acc[2][jj] + bias - mm) * s + be + res.z;
    o.w = (acc[3][jj] + bias - mm) * s + be + res.w;
    *(float4*)&out[((size_t)b * Cc + c) * NN + n0 + ty * 4] = o;
  }
}

extern "C" void kernel_launch(void* const* d_in, const int* in_sizes, int n_in,
                              void* d_out, int out_size, void* d_ws, size_t ws_size,
                              hipStream_t stream) {
  const float* x       = (const float*)d_in[0];
  const float* W1      = (const float*)d_in[1];
  const float* b1      = (const float*)d_in[2];
  const float* bn1     = (const float*)d_in[3];
  const float* Wg      = (const float*)d_in[4];
  const float* att_src = (const float*)d_in[5];
  const float* att_dst = (const float*)d_in[6];
  const float* bg      = (const float*)d_in[7];
  const float* bng     = (const float*)d_in[8];
  const float* W2      = (const float*)d_in[9];
  const float* b2      = (const float*)d_in[10];
  const float* bn2     = (const float*)d_in[11];
  float* out = (float*)d_out;

  float* ws   = (float*)d_ws;
  float* y    = ws;                        // 786432
  float* h    = y + 786432;                // 6291456
  float* sq   = h + 6291456;               // 4096
  float* asrc = sq + 4096;                 // 16384
  float* adst = asrc + 16384;              // 16384
  float* dist = adst + 16384;              // 4194304
  float* g    = dist;                      // 1572864 (reuse; dist dead after topk)
  int*   idx  = (int*)(dist + 4194304);    // 65536 ints

  k_fc1<<<dim3(16, 3, 4), 256, 0, stream>>>(x, W1, b1, bn1, y);
  k_sq<<<Bb * NN, 64, 0, stream>>>(y, sq);
  k_hgemm<<<dim3(64, 24), 256, 0, stream>>>(y, Wg, h);
  k_attn_coef<<<Bb * NN, 256, 0, stream>>>(h, att_src, att_dst, asrc, adst);
  k_dist<<<dim3(16, 16, 4), 256, 0, stream>>>(y, sq, dist);
  k_topk<<<Bb * NN, 64, 0, stream>>>(dist, idx);
  k_gat<<<Bb * NN, 128, 0, stream>>>(h, asrc, adst, idx, bg, bng, g);
  k_fc2<<<dim3(16, 3, 4), 256, 0, stream>>>(g, W2, b2, bn2, x, out);
}